// Round 1
// baseline (121.815 us; speedup 1.0000x reference)
//
#include <hip/hip_runtime.h>

// BilateralFilter3D: 3x3x3 window, replicate pad, sigma_d=120, sigma_r=1.2
// volume: (B,1,128,192,192) float32 -> out same shape.
//
// Round 1: thread-per-voxel, one block per W-row (192 threads, 3 waves).
// d,h wave-uniform -> 9 row bases are SGPRs; only x-offsets are VGPRs.
// Spatial weight folded into exp argument as a compile-time constant.
// den >= 1 always (center weight == 1) so reference's clip(1e-8) is a no-op.

constexpr int Dd = 128;
constexpr int Hh = 192;
constexpr int Ww = 192;

__global__ __launch_bounds__(Ww)
void bilateral3d_kernel(const float* __restrict__ vol, float* __restrict__ out)
{
    const int w = threadIdx.x;   // 0..191, lane-varying
    const int h = blockIdx.x;    // wave-uniform
    const int d = blockIdx.y;    // wave-uniform
    const int b = blockIdx.z;

    const size_t plane   = (size_t)Hh * Ww;
    const size_t volbase = (size_t)b * Dd * plane;

    const float c = vol[volbase + (size_t)d * plane + (size_t)h * Ww + w];

    // replicate padding == clamped indices
    const int zs[3] = { (d > 0) ? d - 1 : 0, d, (d < Dd - 1) ? d + 1 : Dd - 1 };
    const int ys[3] = { (h > 0) ? h - 1 : 0, h, (h < Hh - 1) ? h + 1 : Hh - 1 };
    const int xs[3] = { (w > 0) ? w - 1 : 0, w, (w < Ww - 1) ? w + 1 : Ww - 1 };

    // range kernel scale (natural log units; __expf does the log2e mul + v_exp_f32)
    const float knat = -1.0f / (2.0f * 1.2f * 1.2f);          // -0.347222
    const float kspa = -1.0f / (2.0f * 120.0f * 120.0f);      // -1/28800, * dist^2

    float num = 0.0f, den = 0.0f;

#pragma unroll
    for (int iz = 0; iz < 3; ++iz) {
        const size_t zoff = volbase + (size_t)zs[iz] * plane;
#pragma unroll
        for (int iy = 0; iy < 3; ++iy) {
            const float* __restrict__ row = vol + zoff + (size_t)ys[iy] * Ww;
#pragma unroll
            for (int ix = 0; ix < 3; ++ix) {
                // window-position distance (NOT clamped coords) -> compile-time const
                const int dist2 = (iz - 1) * (iz - 1) + (iy - 1) * (iy - 1)
                                + (ix - 1) * (ix - 1);
                const float cj = kspa * (float)dist2;

                const float n    = row[xs[ix]];
                const float diff = n - c;
                const float arg  = fmaf(diff * diff, knat, cj);
                const float wgt  = __expf(arg);        // native v_exp_f32 path
                num = fmaf(wgt, n, num);
                den += wgt;
            }
        }
    }

    // den >= 1 (center term), so no clamp needed; fast reciprocal is plenty accurate
    out[volbase + (size_t)d * plane + (size_t)h * Ww + w] =
        num * __builtin_amdgcn_rcpf(den);
}

extern "C" void kernel_launch(void* const* d_in, const int* in_sizes, int n_in,
                              void* d_out, int out_size, void* d_ws, size_t ws_size,
                              hipStream_t stream)
{
    const float* vol = (const float*)d_in[0];
    float* out       = (float*)d_out;

    const int B = in_sizes[0] / (Dd * Hh * Ww);   // = 2

    dim3 grid(Hh, Dd, B);   // (192, 128, 2) blocks
    dim3 block(Ww);         // 192 threads = 3 waves, one W-row per block
    bilateral3d_kernel<<<grid, block, 0, stream>>>(vol, out);
}